// Round 2
// baseline (2425.650 us; speedup 1.0000x reference)
//
#include <hip/hip_runtime.h>

#define EPS 1e-5f

// ============================================================
// Buffers (floats): BUF_H (15.36M), BUF_G (15.36M), BUF_R (15.36M)
// ST: iscale/ishift(80+80) bn sc/sh(256+256) rbn sc/sh(256+256) part(4096) HP(614400)
// ============================================================

// ---------- input BN stats: per j = v*3+c over (n,t) ----------
__global__ __launch_bounds__(256) void k_bn_in_stats(const float* __restrict__ x,
    const float* __restrict__ g, const float* __restrict__ b,
    float* __restrict__ iscale, float* __restrict__ ishift) {
  const int j = blockIdx.x;            // 0..74
  const int c = j % 3, v = j / 3;
  const int tid = threadIdx.x;
  float s = 0.f, q = 0.f;
  for (int i = tid; i < 2400; i += 256) {
    const int n = i / 300, t = i % 300;
    const float val = x[(((size_t)n*3 + c)*300 + t)*25 + v];
    s += val; q += val*val;
  }
  __shared__ float rs[256], rq[256];
  rs[tid] = s; rq[tid] = q;
  __syncthreads();
  for (int off = 128; off > 0; off >>= 1) {
    if (tid < off) { rs[tid] += rs[tid+off]; rq[tid] += rq[tid+off]; }
    __syncthreads();
  }
  if (tid == 0) {
    const float mean = rs[0] / 2400.f;
    const float var  = rq[0] / 2400.f - mean*mean;
    const float sc = g[j] * rsqrtf(var + EPS);
    iscale[j] = sc;
    ishift[j] = b[j] - mean*sc;
  }
}

// ---------- fused input-BN apply + fin (3 -> 64 channels) ----------
__global__ __launch_bounds__(256) void k_fin(const float* __restrict__ x,
    const float* __restrict__ iscale, const float* __restrict__ ishift,
    const float* __restrict__ fW, const float* __restrict__ fb,
    float* __restrict__ H) {
  const int n = blockIdx.y;
  const int t0 = blockIdx.x * 10;           // 30 chunks of 10 timesteps
  const int tid = threadIdx.x;
  __shared__ float xn[3][250];
  __shared__ float wsh[64][3];
  __shared__ float bsh[64];
  if (tid < 192) wsh[tid/3][tid%3] = fW[tid];
  if (tid < 64)  bsh[tid] = fb[tid];
  for (int i = tid; i < 750; i += 256) {
    const int c = i / 250, pos = i % 250;
    const int t = t0 + pos/25, v = pos%25;
    const int j = v*3 + c;
    xn[c][pos] = x[(((size_t)n*3 + c)*300 + t)*25 + v] * iscale[j] + ishift[j];
  }
  __syncthreads();
  for (int e = tid; e < 64*250; e += 256) {
    const int o = e / 250, pos = e % 250;
    float acc = bsh[o]
              + xn[0][pos]*wsh[o][0] + xn[1][pos]*wsh[o][1] + xn[2][pos]*wsh[o][2];
    const int t = t0 + pos/25, v = pos%25;
    H[(((size_t)n*64 + o)*300 + t)*25 + v] = acc;
  }
}

// ---------- fused 1x1 conv + graph matmul + partition sum ----------
// G[n,co,t,w] = sum_p sum_v (A[p,v,w]*imp[v,w]) * sum_ci W[(p*cout+co)*cin+ci] * Hin[n,ci,t,v]
__global__ __launch_bounds__(256) void k_conv_graph(const float* __restrict__ Hin,
    const float* __restrict__ W, const float* __restrict__ A, const float* __restrict__ imp,
    float* __restrict__ G, int cin, int cout) {
  const int n = blockIdx.z, c0 = blockIdx.y * 64, t0 = blockIdx.x * 8;
  const int tid = threadIdx.x;
  const int cpair = tid & 31;    // 2 channels each -> 64-channel tile
  const int tg = tid >> 5;       // 0..7 timesteps
  const int t = t0 + tg;
  const bool tvalid = (t < 300);

  __shared__ float A_s[3][25][28];
  __shared__ float x_s[32][8][28];
  __shared__ float W_s[64][33];

  for (int i = tid; i < 3*625; i += 256) {
    const int r = i % 625;
    A_s[i/625][r/25][r%25] = A[i] * imp[r];
  }

  float zacc[2][25];
  #pragma unroll
  for (int r = 0; r < 2; ++r)
    #pragma unroll
    for (int w = 0; w < 25; ++w) zacc[r][w] = 0.f;

  for (int p = 0; p < 3; ++p) {
    float yacc[2][25];
    #pragma unroll
    for (int r = 0; r < 2; ++r)
      #pragma unroll
      for (int v = 0; v < 25; ++v) yacc[r][v] = 0.f;

    for (int cc = 0; cc < cin; cc += 32) {
      __syncthreads();
      // stage x tile: 32 ci x 8 t x 25 v
      for (int i = tid; i < 32*200; i += 256) {
        const int ci = i / 200, pos = i % 200;
        const int tt = pos / 25, v = pos % 25;
        const int tg_t = t0 + tt;
        float val = 0.f;
        if (tg_t < 300) val = Hin[(((size_t)n*cin + cc + ci)*300 + tg_t)*25 + v];
        x_s[ci][tt][v] = val;
      }
      // stage W tile: 64 c x 32 ci
      for (int i = tid; i < 64*32; i += 256) {
        const int c = i >> 5, ci = i & 31;
        W_s[c][ci] = W[((size_t)(p*cout + c0 + c))*cin + cc + ci];
      }
      __syncthreads();
      #pragma unroll 2
      for (int ci = 0; ci < 32; ++ci) {
        float xv[25];
        #pragma unroll
        for (int v = 0; v < 25; ++v) xv[v] = x_s[ci][tg][v];
        const float w0 = W_s[cpair*2][ci];
        const float w1 = W_s[cpair*2+1][ci];
        #pragma unroll
        for (int v = 0; v < 25; ++v) {
          yacc[0][v] += w0 * xv[v];
          yacc[1][v] += w1 * xv[v];
        }
      }
    }
    // apply graph matmul for this partition, accumulate into zacc
    #pragma unroll 1
    for (int v = 0; v < 25; ++v) {
      const float y0 = yacc[0][v], y1 = yacc[1][v];
      #pragma unroll
      for (int w = 0; w < 25; ++w) {
        const float a = A_s[p][v][w];
        zacc[0][w] += y0 * a;
        zacc[1][w] += y1 * a;
      }
    }
  }

  if (tvalid) {
    #pragma unroll
    for (int r = 0; r < 2; ++r) {
      const int c = c0 + cpair*2 + r;
      const size_t base = (((size_t)n*cout + c)*300 + t)*25;
      #pragma unroll
      for (int w = 0; w < 25; ++w) G[base + w] = zacc[r][w];
    }
  }
}

// ---------- plain 1x1 conv (residual path) ----------
__global__ __launch_bounds__(256) void k_conv_res(const float* __restrict__ Hin,
    const float* __restrict__ Wr, float* __restrict__ R, int cin, int cout) {
  const int n = blockIdx.z, c0 = blockIdx.y * 64, t0 = blockIdx.x * 8;
  const int tid = threadIdx.x;
  const int cpair = tid & 31;
  const int tg = tid >> 5;
  const int t = t0 + tg;
  const bool tvalid = (t < 300);

  __shared__ float x_s[32][8][28];
  __shared__ float W_s[64][33];

  float yacc[2][25];
  #pragma unroll
  for (int r = 0; r < 2; ++r)
    #pragma unroll
    for (int v = 0; v < 25; ++v) yacc[r][v] = 0.f;

  for (int cc = 0; cc < cin; cc += 32) {
    __syncthreads();
    for (int i = tid; i < 32*200; i += 256) {
      const int ci = i / 200, pos = i % 200;
      const int tt = pos / 25, v = pos % 25;
      const int tg_t = t0 + tt;
      float val = 0.f;
      if (tg_t < 300) val = Hin[(((size_t)n*cin + cc + ci)*300 + tg_t)*25 + v];
      x_s[ci][tt][v] = val;
    }
    for (int i = tid; i < 64*32; i += 256) {
      const int c = i >> 5, ci = i & 31;
      W_s[c][ci] = Wr[((size_t)(c0 + c))*cin + cc + ci];
    }
    __syncthreads();
    #pragma unroll 2
    for (int ci = 0; ci < 32; ++ci) {
      float xv[25];
      #pragma unroll
      for (int v = 0; v < 25; ++v) xv[v] = x_s[ci][tg][v];
      const float w0 = W_s[cpair*2][ci];
      const float w1 = W_s[cpair*2+1][ci];
      #pragma unroll
      for (int v = 0; v < 25; ++v) {
        yacc[0][v] += w0 * xv[v];
        yacc[1][v] += w1 * xv[v];
      }
    }
  }
  if (tvalid) {
    #pragma unroll
    for (int r = 0; r < 2; ++r) {
      const int c = c0 + cpair*2 + r;
      const size_t base = (((size_t)n*cout + c)*300 + t)*25;
      #pragma unroll
      for (int w = 0; w < 25; ++w) R[base + w] = yacc[r][w];
    }
  }
}

// ---------- BN partial stats of windowed sum S (from G), per (c, n) ----------
__global__ __launch_bounds__(256) void k_bn_part_win(const float* __restrict__ G,
    float* __restrict__ part, int cout) {
  const int c = blockIdx.x, n = blockIdx.y;
  const int tid = threadIdx.x;
  const float* gb = G + ((size_t)n*cout + c)*7500;
  float s = 0.f, q = 0.f;
  for (int i = tid; i < 7500; i += 256) {
    const int ss = i / 25, w = i % 25;
    float S = 0.f;
    if (ss >= 8) {
      #pragma unroll
      for (int d = 0; d < 9; ++d) S += gb[i - d*25];
    } else {
      for (int tt = 0; tt <= ss; ++tt) S += gb[tt*25 + w];
    }
    s += S; q += S*S;
  }
  __shared__ float rs[256], rq[256];
  rs[tid] = s; rq[tid] = q;
  __syncthreads();
  for (int off = 128; off > 0; off >>= 1) {
    if (tid < off) { rs[tid] += rs[tid+off]; rq[tid] += rq[tid+off]; }
    __syncthreads();
  }
  if (tid == 0) {
    part[((size_t)c*8 + n)*2]     = rs[0];
    part[((size_t)c*8 + n)*2 + 1] = rq[0];
  }
}

// ---------- BN partial stats, plain (residual conv output) ----------
__global__ __launch_bounds__(256) void k_bn_part_plain(const float* __restrict__ R,
    float* __restrict__ part, int cout) {
  const int c = blockIdx.x, n = blockIdx.y;
  const int tid = threadIdx.x;
  const float* rb = R + ((size_t)n*cout + c)*7500;
  float s = 0.f, q = 0.f;
  for (int i = tid; i < 7500; i += 256) {
    const float val = rb[i];
    s += val; q += val*val;
  }
  __shared__ float rs[256], rq[256];
  rs[tid] = s; rq[tid] = q;
  __syncthreads();
  for (int off = 128; off > 0; off >>= 1) {
    if (tid < off) { rs[tid] += rs[tid+off]; rq[tid] += rq[tid+off]; }
    __syncthreads();
  }
  if (tid == 0) {
    part[((size_t)c*8 + n)*2]     = rs[0];
    part[((size_t)c*8 + n)*2 + 1] = rq[0];
  }
}

// ---------- finalize BN: scale/shift per channel ----------
__global__ void k_bn_finalize(const float* __restrict__ part,
    const float* __restrict__ g, const float* __restrict__ b,
    float* __restrict__ scale, float* __restrict__ shift, int cout) {
  const int c = blockIdx.x * 64 + threadIdx.x;
  if (c >= cout) return;
  float s = 0.f, q = 0.f;
  for (int n = 0; n < 8; ++n) {
    s += part[((size_t)c*8 + n)*2];
    q += part[((size_t)c*8 + n)*2 + 1];
  }
  const float mean = s / 60000.f;
  const float var  = q / 60000.f - mean*mean;
  const float sc = g[c] * rsqrtf(var + EPS);
  scale[c] = sc;
  shift[c] = b[c] - mean*sc;
}

// ---------- fused window-sum + BN + relu + residual (+relu) ----------
// mode 0: out = relu(bn(S)) ; mode 1: out = relu(relu(bn(S)) + bn_r(R)) ; mode 2: out = relu(relu(bn(S)) + Hres)
__global__ __launch_bounds__(256) void k_apply(const float* __restrict__ G,
    const float* __restrict__ R, const float* __restrict__ Hres,
    const float* __restrict__ scale, const float* __restrict__ shift,
    const float* __restrict__ rscale, const float* __restrict__ rshift,
    float* __restrict__ Out, int cout, int mode) {
  const int bc = blockIdx.x;          // n*cout + c
  const int c = bc % cout;
  const float* gb = G + (size_t)bc * 7500;
  const float sc = scale[c], sh = shift[c];
  float rsc = 0.f, rsh = 0.f;
  if (mode == 1) { rsc = rscale[c]; rsh = rshift[c]; }
  for (int i = threadIdx.x; i < 7500; i += 256) {
    const int ss = i / 25, w = i % 25;
    float S = 0.f;
    if (ss >= 8) {
      #pragma unroll
      for (int d = 0; d < 9; ++d) S += gb[i - d*25];
    } else {
      for (int tt = 0; tt <= ss; ++tt) S += gb[tt*25 + w];
    }
    const float h = fmaxf(S*sc + sh, 0.f);
    float o;
    if (mode == 0)      o = h;
    else if (mode == 1) o = fmaxf(h + (R[(size_t)bc*7500 + i]*rsc + rsh), 0.f);
    else                o = fmaxf(h + Hres[(size_t)bc*7500 + i], 0.f);
    Out[(size_t)bc*7500 + i] = o;
  }
}

// ---------- mean pool over joints ----------
__global__ void k_pool(const float* __restrict__ H, float* __restrict__ HP) {
  const int idx = blockIdx.x*256 + threadIdx.x;   // (n,c,t) flat, 8*256*300
  if (idx >= 8*256*300) return;
  const float* base = H + (size_t)idx * 25;
  float s = 0.f;
  #pragma unroll
  for (int v = 0; v < 25; ++v) s += base[v];
  HP[idx] = s * (1.f/25.f);
}

// ---------- classifier conv ----------
__global__ __launch_bounds__(256) void k_fout(const float* __restrict__ HP,
    const float* __restrict__ fW, const float* __restrict__ fb,
    float* __restrict__ out) {
  const int n = blockIdx.y;
  const int t0 = blockIdx.x * 32;
  const int tid = threadIdx.x;
  __shared__ float hp[256][32];
  for (int i = tid; i < 256*32; i += 256) {
    const int c = i / 32, tt = i % 32;
    const int t = t0 + tt;
    hp[c][tt] = (t < 300) ? HP[((size_t)n*256 + c)*300 + t] : 0.f;
  }
  __syncthreads();
  for (int e = tid; e < 60*32; e += 256) {
    const int o = e / 32, tt = e % 32;
    const int t = t0 + tt;
    if (t >= 300) continue;
    float acc = fb[o];
    for (int c = 0; c < 256; ++c) acc += hp[c][tt] * fW[o*256 + c];
    out[((size_t)n*60 + o)*300 + t] = acc;
  }
}

extern "C" void kernel_launch(void* const* d_in, const int* in_sizes, int n_in,
                              void* d_out, int out_size, void* d_ws, size_t ws_size,
                              hipStream_t stream) {
  (void)in_sizes; (void)n_in; (void)out_size; (void)ws_size;
  const float* x     = (const float*)d_in[0];
  const float* A     = (const float*)d_in[1];
  const float* bng   = (const float*)d_in[2];
  const float* bnb   = (const float*)d_in[3];
  const float* finW  = (const float*)d_in[4];
  const float* finb  = (const float*)d_in[5];
  const float* imp0  = (const float*)d_in[6];
  const float* imp1  = (const float*)d_in[7];
  const float* imp2  = (const float*)d_in[8];
  const float* imp3  = (const float*)d_in[9];
  const float* W0    = (const float*)d_in[10];
  const float* g0    = (const float*)d_in[11];
  const float* b0    = (const float*)d_in[12];
  const float* W1    = (const float*)d_in[13];
  const float* g1    = (const float*)d_in[14];
  const float* b1    = (const float*)d_in[15];
  const float* Wr1   = (const float*)d_in[16];
  const float* gr1   = (const float*)d_in[17];
  const float* br1   = (const float*)d_in[18];
  const float* W2    = (const float*)d_in[19];
  const float* g2    = (const float*)d_in[20];
  const float* b2    = (const float*)d_in[21];
  const float* Wr2   = (const float*)d_in[22];
  const float* gr2   = (const float*)d_in[23];
  const float* br2   = (const float*)d_in[24];
  const float* W3    = (const float*)d_in[25];
  const float* g3    = (const float*)d_in[26];
  const float* b3    = (const float*)d_in[27];
  const float* foutW = (const float*)d_in[28];
  const float* foutb = (const float*)d_in[29];
  float* out = (float*)d_out;

  float* ws    = (float*)d_ws;
  float* BUF_H = ws;
  float* BUF_G = ws + 15360000;
  float* BUF_R = ws + 30720000;
  float* ST    = ws + 46080000;
  float* ISC = ST,        *ISH = ST + 80;
  float* BSC = ST + 160,  *BSH = ST + 416;
  float* RSC = ST + 672,  *RSH = ST + 928;
  float* PART = ST + 1200;           // 4096
  float* HP   = ST + 5312;           // 614400

  k_bn_in_stats<<<75, 256, 0, stream>>>(x, bng, bnb, ISC, ISH);
  k_fin<<<dim3(30, 8), 256, 0, stream>>>(x, ISC, ISH, finW, finb, BUF_H);

  // ---- layer 0: 64 -> 64, no residual, no final relu ----
  k_conv_graph<<<dim3(38, 1, 8), 256, 0, stream>>>(BUF_H, W0, A, imp0, BUF_G, 64, 64);
  k_bn_part_win<<<dim3(64, 8), 256, 0, stream>>>(BUF_G, PART, 64);
  k_bn_finalize<<<1, 64, 0, stream>>>(PART, g0, b0, BSC, BSH, 64);
  k_apply<<<8*64, 256, 0, stream>>>(BUF_G, nullptr, nullptr, BSC, BSH, nullptr, nullptr, BUF_H, 64, 0);

  // ---- layer 1: 64 -> 128, conv+BN residual ----
  k_conv_res<<<dim3(38, 2, 8), 256, 0, stream>>>(BUF_H, Wr1, BUF_R, 64, 128);
  k_bn_part_plain<<<dim3(128, 8), 256, 0, stream>>>(BUF_R, PART, 128);
  k_bn_finalize<<<2, 64, 0, stream>>>(PART, gr1, br1, RSC, RSH, 128);
  k_conv_graph<<<dim3(38, 2, 8), 256, 0, stream>>>(BUF_H, W1, A, imp1, BUF_G, 64, 128);
  k_bn_part_win<<<dim3(128, 8), 256, 0, stream>>>(BUF_G, PART, 128);
  k_bn_finalize<<<2, 64, 0, stream>>>(PART, g1, b1, BSC, BSH, 128);
  k_apply<<<8*128, 256, 0, stream>>>(BUF_G, BUF_R, nullptr, BSC, BSH, RSC, RSH, BUF_H, 128, 1);

  // ---- layer 2: 128 -> 256, conv+BN residual ----
  k_conv_res<<<dim3(38, 4, 8), 256, 0, stream>>>(BUF_H, Wr2, BUF_R, 128, 256);
  k_bn_part_plain<<<dim3(256, 8), 256, 0, stream>>>(BUF_R, PART, 256);
  k_bn_finalize<<<4, 64, 0, stream>>>(PART, gr2, br2, RSC, RSH, 256);
  k_conv_graph<<<dim3(38, 4, 8), 256, 0, stream>>>(BUF_H, W2, A, imp2, BUF_G, 128, 256);
  k_bn_part_win<<<dim3(256, 8), 256, 0, stream>>>(BUF_G, PART, 256);
  k_bn_finalize<<<4, 64, 0, stream>>>(PART, g2, b2, BSC, BSH, 256);
  k_apply<<<8*256, 256, 0, stream>>>(BUF_G, BUF_R, nullptr, BSC, BSH, RSC, RSH, BUF_H, 256, 1);

  // ---- layer 3: 256 -> 256, identity residual ----
  k_conv_graph<<<dim3(38, 4, 8), 256, 0, stream>>>(BUF_H, W3, A, imp3, BUF_G, 256, 256);
  k_bn_part_win<<<dim3(256, 8), 256, 0, stream>>>(BUF_G, PART, 256);
  k_bn_finalize<<<4, 64, 0, stream>>>(PART, g3, b3, BSC, BSH, 256);
  k_apply<<<8*256, 256, 0, stream>>>(BUF_G, nullptr, BUF_H, BSC, BSH, nullptr, nullptr, BUF_H, 256, 2);

  // ---- head: joint mean pool + classifier ----
  k_pool<<<2400, 256, 0, stream>>>(BUF_H, HP);
  k_fout<<<dim3(10, 8), 256, 0, stream>>>(HP, foutW, foutb, out);
}

// Round 3
// 731.428 us; speedup vs baseline: 3.3163x; 3.3163x over previous
//
#include <hip/hip_runtime.h>

#define EPS 1e-5f
typedef unsigned short u16;
typedef __attribute__((ext_vector_type(8))) short short8;
typedef __attribute__((ext_vector_type(4))) float f32x4;

__device__ __forceinline__ float bf2f(u16 u) {
  union { unsigned int i; float f; } c; c.i = ((unsigned int)u) << 16; return c.f;
}
__device__ __forceinline__ u16 f2bf(float f) {
  union { float f; unsigned int i; } c; c.f = f;
  unsigned int u = c.i;
  u += 0x7fffu + ((u >> 16) & 1u);   // round-to-nearest-even
  return (u16)(u >> 16);
}

// ---------- input BN stats: per j = v*3+c over (n,t) ----------
__global__ __launch_bounds__(256) void k_bn_in_stats(const float* __restrict__ x,
    const float* __restrict__ g, const float* __restrict__ b,
    float* __restrict__ iscale, float* __restrict__ ishift) {
  const int j = blockIdx.x;            // 0..74
  const int c = j % 3, v = j / 3;
  const int tid = threadIdx.x;
  float s = 0.f, q = 0.f;
  for (int i = tid; i < 2400; i += 256) {
    const int n = i / 300, t = i % 300;
    const float val = x[(((size_t)n*3 + c)*300 + t)*25 + v];
    s += val; q += val*val;
  }
  __shared__ float rs[256], rq[256];
  rs[tid] = s; rq[tid] = q;
  __syncthreads();
  for (int off = 128; off > 0; off >>= 1) {
    if (tid < off) { rs[tid] += rs[tid+off]; rq[tid] += rq[tid+off]; }
    __syncthreads();
  }
  if (tid == 0) {
    const float mean = rs[0] / 2400.f;
    const float var  = rq[0] / 2400.f - mean*mean;
    const float sc = g[j] * rsqrtf(var + EPS);
    iscale[j] = sc;
    ishift[j] = b[j] - mean*sc;
  }
}

// ---------- fused input-BN apply + fin (3 -> 64), writes bf16 H_ct ----------
__global__ __launch_bounds__(256) void k_fin(const float* __restrict__ x,
    const float* __restrict__ iscale, const float* __restrict__ ishift,
    const float* __restrict__ fW, const float* __restrict__ fb,
    u16* __restrict__ H) {
  const int n = blockIdx.y;
  const int t0 = blockIdx.x * 10;
  const int tid = threadIdx.x;
  __shared__ float xn[3][250];
  __shared__ float wsh[64][3];
  __shared__ float bsh[64];
  if (tid < 192) wsh[tid/3][tid%3] = fW[tid];
  if (tid < 64)  bsh[tid] = fb[tid];
  for (int i = tid; i < 750; i += 256) {
    const int c = i / 250, pos = i % 250;
    const int t = t0 + pos/25, v = pos%25;
    const int j = v*3 + c;
    xn[c][pos] = x[(((size_t)n*3 + c)*300 + t)*25 + v] * iscale[j] + ishift[j];
  }
  __syncthreads();
  for (int e = tid; e < 64*250; e += 256) {
    const int o = e / 250, pos = e % 250;
    float acc = bsh[o]
              + xn[0][pos]*wsh[o][0] + xn[1][pos]*wsh[o][1] + xn[2][pos]*wsh[o][2];
    const int t = t0 + pos/25, v = pos%25;
    H[(((size_t)n*64 + o)*300 + t)*25 + v] = f2bf(acc);
  }
}

// ---------- prep: A' = A * imp per layer (fp32) ----------
__global__ void k_prep_A(const float* __restrict__ A,
    const float* __restrict__ i0, const float* __restrict__ i1,
    const float* __restrict__ i2, const float* __restrict__ i3,
    float* __restrict__ Ap) {
  const int idx = blockIdx.x*256 + threadIdx.x;
  if (idx >= 7500) return;
  const int layer = idx / 1875, r = idx % 1875;
  const int vw = r % 625;
  const float* imp = (layer==0) ? i0 : (layer==1) ? i1 : (layer==2) ? i2 : i3;
  Ap[idx] = A[r] * imp[vw];
}

// ---------- prep: Wt[co][p*cin+ci] = bf16(W[(p*cout+co)*cin+ci]) ----------
__global__ void k_prep_w(const float* __restrict__ W, u16* __restrict__ Wt,
    int cin, int cout, int P) {
  const int idx = blockIdx.x*256 + threadIdx.x;
  const int K = P*cin;
  if (idx >= cout*K) return;
  const int co = idx / K, k = idx % K;
  const int p = k / cin, ci = k % cin;
  Wt[idx] = f2bf(W[((size_t)(p*cout + co))*cin + ci]);
}

// ---------- xa: per (n,t): XA[n][t*25+w][p*cin+ci] = sum_v H[ci][t][v] * A'[p][v][w] ----------
// also (optional) Hmk[n][t*25+v][ci] = H[ci][t][v]  (K-major copy for residual GEMM)
__global__ __launch_bounds__(256) void k_xa(const u16* __restrict__ H,
    const float* __restrict__ Ap, u16* __restrict__ XA, u16* Hmk, int cin) {
  const int t = blockIdx.x, n = blockIdx.y;
  const int tid = threadIdx.x;
  __shared__ float xs[256][26];
  __shared__ float Asl[1875];
  for (int i = tid; i < 1875; i += 256) Asl[i] = Ap[i];
  for (int i = tid; i < cin*25; i += 256) {
    const int ci = i / 25, v = i % 25;
    xs[ci][v] = bf2f(H[(((size_t)n*cin + ci)*300 + t)*25 + v]);
  }
  __syncthreads();
  if (Hmk) {
    for (int j = tid; j < 25*cin; j += 256) {
      const int v = j / cin, ci = j % cin;
      Hmk[((size_t)n*7500 + t*25 + v)*cin + ci] = f2bf(xs[ci][v]);
    }
  }
  const int K = 3*cin;
  for (int k = tid; k < K; k += 256) {
    const int p = k / cin, ci = k % cin;
    float xr[25];
    #pragma unroll
    for (int v = 0; v < 25; ++v) xr[v] = xs[ci][v];
    const float* Ab = &Asl[p*625];
    #pragma unroll 1
    for (int w = 0; w < 25; ++w) {
      float s = 0.f;
      #pragma unroll
      for (int v = 0; v < 25; ++v) s += xr[v] * Ab[v*25 + w];
      XA[((size_t)n*7500 + t*25 + w)*K + k] = f2bf(s);
    }
  }
}

// ---------- bf16 MFMA GEMM ----------
// A: bf16, per n at Asrc + n*7500*K, row m (7500 rows), k contiguous
// B: Wt bf16 [N][K]  (k contiguous)
// C: out[(n*N+co)*7500 + m], fp32 (store_bf16=0) or bf16 (=1)
__global__ __launch_bounds__(256) void k_gemm(const u16* __restrict__ Asrc,
    const u16* __restrict__ Bsrc, float* __restrict__ Cf, u16* __restrict__ Cb,
    int K, int N, int store_bf16) {
  const int m0 = blockIdx.x * 128;
  const int n0 = blockIdx.y * 64;
  const int n  = blockIdx.z;
  const int tid = threadIdx.x;
  const int lane = tid & 63, wid = tid >> 6;
  const int wm = (wid & 1) * 64, wn = (wid >> 1) * 32;

  __shared__ u16 As[128*64];
  __shared__ u16 Bs[64*64];

  const u16* An = Asrc + (size_t)n * 7500 * K;

  f32x4 acc[4][2];
  #pragma unroll
  for (int mi = 0; mi < 4; ++mi)
    #pragma unroll
    for (int ni = 0; ni < 2; ++ni) acc[mi][ni] = (f32x4){0.f,0.f,0.f,0.f};

  const int nkt = K >> 6;
  for (int kt = 0; kt < nkt; ++kt) {
    const int kbase = kt * 64;
    __syncthreads();
    // stage A tile: 128 rows x 64 k, XOR-swizzled chunks (16B granularity)
    #pragma unroll
    for (int i = 0; i < 4; ++i) {
      const int idx = tid + i*256;            // 0..1023
      const int r = idx >> 3, c = idx & 7;
      int m = m0 + r; if (m > 7499) m = 7499;
      const short8 val = *(const short8*)(An + (size_t)m*K + kbase + c*8);
      *(short8*)&As[r*64 + ((c ^ (r & 7)) * 8)] = val;
    }
    // stage B tile: 64 rows x 64 k
    #pragma unroll
    for (int i = 0; i < 2; ++i) {
      const int idx = tid + i*256;            // 0..511
      const int r = idx >> 3, c = idx & 7;
      const short8 val = *(const short8*)(Bsrc + (size_t)(n0 + r)*K + kbase + c*8);
      *(short8*)&Bs[r*64 + ((c ^ (r & 7)) * 8)] = val;
    }
    __syncthreads();
    #pragma unroll
    for (int kc = 0; kc < 2; ++kc) {
      const int kchunk = kc*4 + (lane >> 4);  // 16B chunk index within the 64-k row
      short8 a[4], b[2];
      #pragma unroll
      for (int mi = 0; mi < 4; ++mi) {
        const int m = wm + mi*16 + (lane & 15);
        a[mi] = *(const short8*)&As[m*64 + ((kchunk ^ (m & 7)) * 8)];
      }
      #pragma unroll
      for (int ni = 0; ni < 2; ++ni) {
        const int r = wn + ni*16 + (lane & 15);
        b[ni] = *(const short8*)&Bs[r*64 + ((kchunk ^ (r & 7)) * 8)];
      }
      #pragma unroll
      for (int mi = 0; mi < 4; ++mi)
        #pragma unroll
        for (int ni = 0; ni < 2; ++ni)
          acc[mi][ni] = __builtin_amdgcn_mfma_f32_16x16x32_bf16(a[mi], b[ni], acc[mi][ni], 0, 0, 0);
    }
  }

  // epilogue: D col=lane&15 (co), rows = (lane>>4)*4 + reg -> per-lane 4 consecutive m
  const int mrow = (lane >> 4) * 4;
  #pragma unroll
  for (int mi = 0; mi < 4; ++mi) {
    const int mb = m0 + wm + mi*16 + mrow;
    if (mb >= 7500) continue;
    #pragma unroll
    for (int ni = 0; ni < 2; ++ni) {
      const int co = n0 + wn + ni*16 + (lane & 15);
      const size_t off = ((size_t)n * N + co) * 7500 + mb;
      if (store_bf16) {
        unsigned long long pk =
            (unsigned long long)f2bf(acc[mi][ni][0]) |
            ((unsigned long long)f2bf(acc[mi][ni][1]) << 16) |
            ((unsigned long long)f2bf(acc[mi][ni][2]) << 32) |
            ((unsigned long long)f2bf(acc[mi][ni][3]) << 48);
        *(unsigned long long*)&Cb[off] = pk;
      } else {
        *(f32x4*)&Cf[off] = acc[mi][ni];
      }
    }
  }
}

// ---------- BN partial stats of windowed sum S (from fp32 Z), per (c,n) ----------
__global__ __launch_bounds__(256) void k_bn_part_win(const float* __restrict__ G,
    float* __restrict__ part, int cout) {
  const int c = blockIdx.x, n = blockIdx.y;
  const int tid = threadIdx.x;
  const float* gb = G + ((size_t)n*cout + c)*7500;
  float s = 0.f, q = 0.f;
  for (int i = tid; i < 7500; i += 256) {
    const int ss = i / 25, w = i % 25;
    float S = 0.f;
    if (ss >= 8) {
      #pragma unroll
      for (int d = 0; d < 9; ++d) S += gb[i - d*25];
    } else {
      for (int tt = 0; tt <= ss; ++tt) S += gb[tt*25 + w];
    }
    s += S; q += S*S;
  }
  __shared__ float rs[256], rq[256];
  rs[tid] = s; rq[tid] = q;
  __syncthreads();
  for (int off = 128; off > 0; off >>= 1) {
    if (tid < off) { rs[tid] += rs[tid+off]; rq[tid] += rq[tid+off]; }
    __syncthreads();
  }
  if (tid == 0) {
    part[((size_t)c*8 + n)*2]     = rs[0];
    part[((size_t)c*8 + n)*2 + 1] = rq[0];
  }
}

// ---------- BN partial stats, plain (bf16 residual R) ----------
__global__ __launch_bounds__(256) void k_bn_part_plain(const u16* __restrict__ R,
    float* __restrict__ part, int cout) {
  const int c = blockIdx.x, n = blockIdx.y;
  const int tid = threadIdx.x;
  const u16* rb = R + ((size_t)n*cout + c)*7500;
  float s = 0.f, q = 0.f;
  for (int i = tid; i < 7500; i += 256) {
    const float val = bf2f(rb[i]);
    s += val; q += val*val;
  }
  __shared__ float rs[256], rq[256];
  rs[tid] = s; rq[tid] = q;
  __syncthreads();
  for (int off = 128; off > 0; off >>= 1) {
    if (tid < off) { rs[tid] += rs[tid+off]; rq[tid] += rq[tid+off]; }
    __syncthreads();
  }
  if (tid == 0) {
    part[((size_t)c*8 + n)*2]     = rs[0];
    part[((size_t)c*8 + n)*2 + 1] = rq[0];
  }
}

// ---------- finalize BN ----------
__global__ void k_bn_finalize(const float* __restrict__ part,
    const float* __restrict__ g, const float* __restrict__ b,
    float* __restrict__ scale, float* __restrict__ shift, int cout) {
  const int c = blockIdx.x * 64 + threadIdx.x;
  if (c >= cout) return;
  float s = 0.f, q = 0.f;
  for (int n = 0; n < 8; ++n) {
    s += part[((size_t)c*8 + n)*2];
    q += part[((size_t)c*8 + n)*2 + 1];
  }
  const float mean = s / 60000.f;
  const float var  = q / 60000.f - mean*mean;
  const float sc = g[c] * rsqrtf(var + EPS);
  scale[c] = sc;
  shift[c] = b[c] - mean*sc;
}

// ---------- fused window-sum + BN + relu + residual; writes bf16 H ----------
// mode 0: relu(bn(S)); mode 1: relu(relu(bn(S)) + bn_r(R)); mode 2: relu(relu(bn(S)) + Hres)
__global__ __launch_bounds__(256) void k_apply(const float* __restrict__ G,
    const u16* __restrict__ Rb, const u16* Hres,
    const float* __restrict__ scale, const float* __restrict__ shift,
    const float* __restrict__ rscale, const float* __restrict__ rshift,
    u16* Out, int cout, int mode) {
  const int bc = blockIdx.x;          // n*cout + c
  const int c = bc % cout;
  const float* gb = G + (size_t)bc * 7500;
  const float sc = scale[c], sh = shift[c];
  float rsc = 0.f, rsh = 0.f;
  if (mode == 1) { rsc = rscale[c]; rsh = rshift[c]; }
  for (int i = threadIdx.x; i < 7500; i += 256) {
    const int ss = i / 25, w = i % 25;
    float S = 0.f;
    if (ss >= 8) {
      #pragma unroll
      for (int d = 0; d < 9; ++d) S += gb[i - d*25];
    } else {
      for (int tt = 0; tt <= ss; ++tt) S += gb[tt*25 + w];
    }
    const float h = fmaxf(S*sc + sh, 0.f);
    float o;
    if (mode == 0)      o = h;
    else if (mode == 1) o = fmaxf(h + (bf2f(Rb[(size_t)bc*7500 + i])*rsc + rsh), 0.f);
    else                o = fmaxf(h + bf2f(Hres[(size_t)bc*7500 + i]), 0.f);
    Out[(size_t)bc*7500 + i] = f2bf(o);
  }
}

// ---------- mean pool over joints (bf16 in, fp32 out) ----------
__global__ void k_pool(const u16* __restrict__ H, float* __restrict__ HP) {
  const int idx = blockIdx.x*256 + threadIdx.x;   // (n,c,t) flat
  if (idx >= 8*256*300) return;
  const u16* base = H + (size_t)idx * 25;
  float s = 0.f;
  #pragma unroll
  for (int v = 0; v < 25; ++v) s += bf2f(base[v]);
  HP[idx] = s * (1.f/25.f);
}

// ---------- classifier conv ----------
__global__ __launch_bounds__(256) void k_fout(const float* __restrict__ HP,
    const float* __restrict__ fW, const float* __restrict__ fb,
    float* __restrict__ out) {
  const int n = blockIdx.y;
  const int t0 = blockIdx.x * 32;
  const int tid = threadIdx.x;
  __shared__ float hp[256][32];
  for (int i = tid; i < 256*32; i += 256) {
    const int c = i / 32, tt = i % 32;
    const int t = t0 + tt;
    hp[c][tt] = (t < 300) ? HP[((size_t)n*256 + c)*300 + t] : 0.f;
  }
  __syncthreads();
  for (int e = tid; e < 60*32; e += 256) {
    const int o = e / 32, tt = e % 32;
    const int t = t0 + tt;
    if (t >= 300) continue;
    float acc = fb[o];
    for (int c = 0; c < 256; ++c) acc += hp[c][tt] * fW[o*256 + c];
    out[((size_t)n*60 + o)*300 + t] = acc;
  }
}

extern "C" void kernel_launch(void* const* d_in, const int* in_sizes, int n_in,
                              void* d_out, int out_size, void* d_ws, size_t ws_size,
                              hipStream_t stream) {
  (void)in_sizes; (void)n_in; (void)out_size; (void)ws_size;
  const float* x     = (const float*)d_in[0];
  const float* A     = (const float*)d_in[1];
  const float* bng   = (const float*)d_in[2];
  const float* bnb   = (const float*)d_in[3];
  const float* finW  = (const float*)d_in[4];
  const float* finb  = (const float*)d_in[5];
  const float* imp0  = (const float*)d_in[6];
  const float* imp1  = (const float*)d_in[7];
  const float* imp2  = (const float*)d_in[8];
  const float* imp3  = (const float*)d_in[9];
  const float* W0    = (const float*)d_in[10];
  const float* g0    = (const float*)d_in[11];
  const float* b0    = (const float*)d_in[12];
  const float* W1    = (const float*)d_in[13];
  const float* g1    = (const float*)d_in[14];
  const float* b1    = (const float*)d_in[15];
  const float* Wr1   = (const float*)d_in[16];
  const float* gr1   = (const float*)d_in[17];
  const float* br1   = (const float*)d_in[18];
  const float* W2    = (const float*)d_in[19];
  const float* g2    = (const float*)d_in[20];
  const float* b2    = (const float*)d_in[21];
  const float* Wr2   = (const float*)d_in[22];
  const float* gr2   = (const float*)d_in[23];
  const float* br2   = (const float*)d_in[24];
  const float* W3    = (const float*)d_in[25];
  const float* g3    = (const float*)d_in[26];
  const float* b3    = (const float*)d_in[27];
  const float* foutW = (const float*)d_in[28];
  const float* foutb = (const float*)d_in[29];
  float* out = (float*)d_out;

  char* base = (char*)d_ws;
  float* Z    = (float*)base;                      // 15,360,000 f32 (61.44 MB)
  u16*   Hmk  = (u16*)base;                        // overlay in Z region (dead before Z written)
  u16*   BIGU = (u16*)(base + 61440000);           // 46,080,000 u16 (92.16 MB)
  u16*   XA   = BIGU;
  u16*   Rb   = BIGU + 23040000;                   // bf16 residual (only layers 1,2: XA <= 23.04M u16)
  u16*   Hct  = (u16*)(base + 153600000);          // 15,360,000 u16 (30.72 MB)
  float* HP   = (float*)(base + 184320000);        // 614,400 f32
  u16*   WT   = (u16*)(base + 186777600);          // 372,736 u16
  float* Ap   = (float*)(base + 187523072);        // 7,500 f32
  float* ST   = Ap + 7500;
  float* ISC = ST,         *ISH = ST + 80;
  float* BSC = ST + 160,   *BSH = ST + 416;
  float* RSC = ST + 672,   *RSH = ST + 928;
  float* PART = ST + 1200;                         // 4096

  u16* W0t  = WT;            // 64 x 192
  u16* W1t  = WT + 12288;    // 128 x 192
  u16* Wr1t = WT + 36864;    // 128 x 64
  u16* W2t  = WT + 45056;    // 256 x 384
  u16* Wr2t = WT + 143360;   // 256 x 128
  u16* W3t  = WT + 176128;   // 256 x 768

  // ---- prep ----
  k_prep_A<<<30, 256, 0, stream>>>(A, imp0, imp1, imp2, imp3, Ap);
  k_prep_w<<<48,  256, 0, stream>>>(W0,  W0t,  64,  64,  3);
  k_prep_w<<<96,  256, 0, stream>>>(W1,  W1t,  64,  128, 3);
  k_prep_w<<<32,  256, 0, stream>>>(Wr1, Wr1t, 64,  128, 1);
  k_prep_w<<<384, 256, 0, stream>>>(W2,  W2t,  128, 256, 3);
  k_prep_w<<<128, 256, 0, stream>>>(Wr2, Wr2t, 128, 256, 1);
  k_prep_w<<<768, 256, 0, stream>>>(W3,  W3t,  256, 256, 3);

  k_bn_in_stats<<<75, 256, 0, stream>>>(x, bng, bnb, ISC, ISH);
  k_fin<<<dim3(30, 8), 256, 0, stream>>>(x, ISC, ISH, finW, finb, Hct);

  // ---- layer 0: 64 -> 64, no residual, no final relu ----
  k_xa<<<dim3(300, 8), 256, 0, stream>>>(Hct, Ap, XA, nullptr, 64);
  k_gemm<<<dim3(59, 1, 8), 256, 0, stream>>>(XA, W0t, Z, nullptr, 192, 64, 0);
  k_bn_part_win<<<dim3(64, 8), 256, 0, stream>>>(Z, PART, 64);
  k_bn_finalize<<<1, 64, 0, stream>>>(PART, g0, b0, BSC, BSH, 64);
  k_apply<<<8*64, 256, 0, stream>>>(Z, nullptr, nullptr, BSC, BSH, nullptr, nullptr, Hct, 64, 0);

  // ---- layer 1: 64 -> 128 ----
  k_xa<<<dim3(300, 8), 256, 0, stream>>>(Hct, Ap + 1875, XA, Hmk, 64);
  k_gemm<<<dim3(59, 2, 8), 256, 0, stream>>>(Hmk, Wr1t, nullptr, Rb, 64, 128, 1);
  k_bn_part_plain<<<dim3(128, 8), 256, 0, stream>>>(Rb, PART, 128);
  k_bn_finalize<<<2, 64, 0, stream>>>(PART, gr1, br1, RSC, RSH, 128);
  k_gemm<<<dim3(59, 2, 8), 256, 0, stream>>>(XA, W1t, Z, nullptr, 192, 128, 0);
  k_bn_part_win<<<dim3(128, 8), 256, 0, stream>>>(Z, PART, 128);
  k_bn_finalize<<<2, 64, 0, stream>>>(PART, g1, b1, BSC, BSH, 128);
  k_apply<<<8*128, 256, 0, stream>>>(Z, Rb, nullptr, BSC, BSH, RSC, RSH, Hct, 128, 1);

  // ---- layer 2: 128 -> 256 ----
  k_xa<<<dim3(300, 8), 256, 0, stream>>>(Hct, Ap + 3750, XA, Hmk, 128);
  k_gemm<<<dim3(59, 4, 8), 256, 0, stream>>>(Hmk, Wr2t, nullptr, Rb, 128, 256, 1);
  k_bn_part_plain<<<dim3(256, 8), 256, 0, stream>>>(Rb, PART, 256);
  k_bn_finalize<<<4, 64, 0, stream>>>(PART, gr2, br2, RSC, RSH, 256);
  k_gemm<<<dim3(59, 4, 8), 256, 0, stream>>>(XA, W2t, Z, nullptr, 384, 256, 0);
  k_bn_part_win<<<dim3(256, 8), 256, 0, stream>>>(Z, PART, 256);
  k_bn_finalize<<<4, 64, 0, stream>>>(PART, g2, b2, BSC, BSH, 256);
  k_apply<<<8*256, 256, 0, stream>>>(Z, Rb, nullptr, BSC, BSH, RSC, RSH, Hct, 256, 1);

  // ---- layer 3: 256 -> 256, identity residual ----
  k_xa<<<dim3(300, 8), 256, 0, stream>>>(Hct, Ap + 5625, XA, nullptr, 256);
  k_gemm<<<dim3(59, 4, 8), 256, 0, stream>>>(XA, W3t, Z, nullptr, 768, 256, 0);
  k_bn_part_win<<<dim3(256, 8), 256, 0, stream>>>(Z, PART, 256);
  k_bn_finalize<<<4, 64, 0, stream>>>(PART, g3, b3, BSC, BSH, 256);
  k_apply<<<8*256, 256, 0, stream>>>(Z, nullptr, Hct, BSC, BSH, nullptr, nullptr, Hct, 256, 2);

  // ---- head ----
  k_pool<<<2400, 256, 0, stream>>>(Hct, HP);
  k_fout<<<dim3(10, 8), 256, 0, stream>>>(HP, foutW, foutb, out);
}